// Round 7
// baseline (516.664 us; speedup 1.0000x reference)
//
#include <hip/hip_runtime.h>
#include <hip/hip_bf16.h>
#include <hip/hip_fp16.h>

#define NPOS 784
#define WDIM 28

// ---------------- kernel 1: fused 1x1-conv q/k/v -> d_ws ----------------
// All fp32. Layout [bh][kl][m], m contiguous (16 floats = 64 B per row).
__global__ __launch_bounds__(256) void qkv_kernel(
    const float* __restrict__ x,
    const float* __restrict__ wq, const float* __restrict__ bq,
    const float* __restrict__ wk, const float* __restrict__ bk,
    const float* __restrict__ wv, const float* __restrict__ bv,
    float* __restrict__ Q, float* __restrict__ K, float* __restrict__ V)
{
    int idx = blockIdx.x * 256 + threadIdx.x;        // grid covers exactly 401408
    int ij = idx % NPOS;
    int oc = (idx / NPOS) & 127;
    int b  = idx / (NPOS * 128);

    float x0 = x[(b * 3 + 0) * NPOS + ij];
    float x1 = x[(b * 3 + 1) * NPOS + ij];
    float x2 = x[(b * 3 + 2) * NPOS + ij];

    float q = bq[oc] + wq[oc*3+0]*x0 + wq[oc*3+1]*x1 + wq[oc*3+2]*x2;
    float k = bk[oc] + wk[oc*3+0]*x0 + wk[oc*3+1]*x1 + wk[oc*3+2]*x2;
    float v = bv[oc] + wv[oc*3+0]*x0 + wv[oc*3+1]*x1 + wv[oc*3+2]*x2;

    int m = oc >> 3, h = oc & 7;                     // oc = m*HEADS + h
    int dst = ((b * 8 + h) * NPOS + ij) * 16 + m;
    Q[dst] = q; K[dst] = k; V[dst] = v;
}

// ---------------- kernel 2: attention, block = (b, ij), wave-owned heads ----
// Wave w processes heads {w, w+4} with NO barriers inside the head loop
// (same-wave LDS ordering is hardware-guaranteed). Scores staged fp16x2 in a
// per-wave LDS strip; one exp per (g,key); projection fused, no atomics.
__global__ __launch_bounds__(256, 4) void attn_kernel(
    const float* __restrict__ Q, const float* __restrict__ K, const float* __restrict__ V,
    const float* __restrict__ w_out, const float* __restrict__ b_out,
    const float* __restrict__ rw1, const float* __restrict__ rb1,
    const float* __restrict__ rga, const float* __restrict__ rbe,
    const float* __restrict__ rw2, const float* __restrict__ rb2,
    const float* __restrict__ cw1, const float* __restrict__ cb1,
    const float* __restrict__ cga, const float* __restrict__ cbe,
    const float* __restrict__ cw2, const float* __restrict__ cb2,
    float* __restrict__ out)
{
    __shared__ float   Er[8 * 110], Ec[8 * 110];     // embed tables, transposed [m][d]
    __shared__ __half2 scp[4][2][788];               // [wave][pair][key]: (s0,s1),(s2,s3)
    __shared__ float4  Rt[4][56];                    // per-wave packed rotation terms
    __shared__ float   ovs[8][4][16];                // [h][g][m]

    const int t    = threadIdx.x;
    const int b    = blockIdx.x / NPOS;
    const int ij   = blockIdx.x % NPOS;
    const int iq   = ij / WDIM, jq = ij % WDIM;
    const int wave = t >> 6, lane = t & 63;
    const float scale = 0.57735026918962576f;        // 1/sqrt(CIN=3)

    // ---- embedding-MLP tables (once per block), transposed to [m][110] ----
    {
        int d = -1;
        const float *w1 = rw1, *b1 = rb1, *ga = rga, *be = rbe, *w2 = rw2, *b2 = rb2;
        float* E = Er;
        if (t < 110) { d = t; }
        else if (t >= 128 && t < 238) { d = t - 128; w1 = cw1; b1 = cb1; ga = cga; be = cbe; w2 = cw2; b2 = cb2; E = Ec; }
        if (d >= 0) {
            float u = (d < 55) ? (-1.0f + (float)d * (2.0f / 54.0f))
                               : -(-1.0f + (float)(d - 55) * (2.0f / 54.0f));
            float hb[16], mu = 0.0f;
#pragma unroll
            for (int c = 0; c < 16; ++c) { hb[c] = u * w1[c] + b1[c]; mu += hb[c]; }
            mu *= (1.0f / 16.0f);
            float var = 0.0f;
#pragma unroll
            for (int c = 0; c < 16; ++c) { float dv = hb[c] - mu; var += dv * dv; }
            var *= (1.0f / 16.0f);
            float rstd = rsqrtf(var + 1e-5f);
#pragma unroll
            for (int c = 0; c < 16; ++c) {
                float hn = ga[c] * (hb[c] - mu) * rstd + be[c];
                hb[c] = hn / (1.0f + __expf(-hn));
            }
#pragma unroll
            for (int m = 0; m < 8; ++m) {
                float e = b2[m];
#pragma unroll
                for (int c = 0; c < 16; ++c) e += hb[c] * w2[m * 16 + c];
                E[m * 110 + d] = e;                  // transposed
            }
        }
    }
    __syncthreads();                                 // E ready for all waves

    for (int hi = 0; hi < 2; ++hi) {
        const int h  = wave + hi * 4;
        const int bh = b * 8 + h;

        // q in registers (uniform per block-head; broadcast loads, L2-hot)
        float q[16];
        {
            const float4* qp = (const float4*)(Q + (size_t)(bh * NPOS + ij) * 16);
            float4 q0 = qp[0], q1 = qp[1], q2 = qp[2], q3 = qp[3];
            q[0]=q0.x; q[1]=q0.y; q[2]=q0.z; q[3]=q0.w;
            q[4]=q1.x; q[5]=q1.y; q[6]=q1.z; q[7]=q1.w;
            q[8]=q2.x; q[9]=q2.y; q[10]=q2.z; q[11]=q2.w;
            q[12]=q3.x; q[13]=q3.y; q[14]=q3.z; q[15]=q3.w;
        }

        // packed rotation table: Rt[d] = scale*(arow[d], acol[d], arow[d+55], acol[d+55])
        if (lane < 55) {
            int d = lane;
            float ar = 0, ac = 0, ar5 = 0, ac5 = 0;
#pragma unroll
            for (int mm = 0; mm < 8; ++mm) {
                float ql = q[mm], qh = q[8 + mm];
                ar  += ql * Er[mm * 110 + d];
                ar5 += ql * Er[mm * 110 + d + 55];
                ac  += qh * Ec[mm * 110 + d];
                ac5 += qh * Ec[mm * 110 + d + 55];
            }
            Rt[wave][d] = make_float4(ar * scale, ac * scale, ar5 * scale, ac5 * scale);
        }
        // same-wave LDS write->read: in-order per wave, no barrier needed

        // score pass: lane covers keys it*64+lane; fp16x2 staging + max tracking
        float m0 = -3.4e38f, m1 = -3.4e38f, m2 = -3.4e38f, m3 = -3.4e38f;
#pragma unroll
        for (int it = 0; it < 13; ++it) {
            int k = it * 64 + lane;
            if (k < NPOS) {
                const float4* kp = (const float4*)(K + (size_t)(bh * NPOS + k) * 16);
                float4 k0 = kp[0], k1 = kp[1], k2 = kp[2], k3 = kp[3];
                float c = q[0]*k0.x + q[1]*k0.y + q[2]*k0.z + q[3]*k0.w
                        + q[4]*k1.x + q[5]*k1.y + q[6]*k1.z + q[7]*k1.w
                        + q[8]*k2.x + q[9]*k2.y + q[10]*k2.z + q[11]*k2.w
                        + q[12]*k3.x + q[13]*k3.y + q[14]*k3.z + q[15]*k3.w;
                c *= scale;
                int row = k / WDIM, col = k - row * WDIM;
                float4 rr = Rt[wave][row - iq + 27];
                float4 rc = Rt[wave][col - jq + 27];
                float s0 = c + rr.x + rc.y;
                float s1 = c + rc.z + rr.y;
                float s2 = c + rr.z + rc.w;
                float s3 = c + rc.x + rr.w;
                scp[wave][0][k] = __floats2half2_rn(s0, s1);
                scp[wave][1][k] = __floats2half2_rn(s2, s3);
                m0 = fmaxf(m0, s0); m1 = fmaxf(m1, s1);
                m2 = fmaxf(m2, s2); m3 = fmaxf(m3, s3);
            }
        }
        // butterfly max: every lane ends with the wave max
#pragma unroll
        for (int off = 1; off < 64; off <<= 1) {
            m0 = fmaxf(m0, __shfl_xor(m0, off, 64));
            m1 = fmaxf(m1, __shfl_xor(m1, off, 64));
            m2 = fmaxf(m2, __shfl_xor(m2, off, 64));
            m3 = fmaxf(m3, __shfl_xor(m3, off, 64));
        }

        // PV: lane = (g = lane>>4, ch = lane&15); one exp per (g,key);
        // V as 4x float4 (16 keys x 64B distinct per 4 instrs, coalesced).
        const int g = lane >> 4, ch = lane & 15;
        const float M   = (g == 0) ? m0 : (g == 1) ? m1 : (g == 2) ? m2 : m3;
        const int pair  = g >> 1;
        const int hihalf = g & 1;
        float acc[16];
#pragma unroll
        for (int m = 0; m < 16; ++m) acc[m] = 0.0f;
        float ps = 0.0f;
        for (int s = 0; s < 49; ++s) {
            int k = s * 16 + ch;
            float2 sv = __half22float2(scp[wave][pair][k]);
            float p = __expf((hihalf ? sv.y : sv.x) - M);
            ps += p;
            const float4* vp = (const float4*)(V + (size_t)(bh * NPOS + k) * 16);
            float4 v0 = vp[0], v1 = vp[1], v2 = vp[2], v3 = vp[3];
            acc[0]  += p * v0.x; acc[1]  += p * v0.y; acc[2]  += p * v0.z; acc[3]  += p * v0.w;
            acc[4]  += p * v1.x; acc[5]  += p * v1.y; acc[6]  += p * v1.z; acc[7]  += p * v1.w;
            acc[8]  += p * v2.x; acc[9]  += p * v2.y; acc[10] += p * v2.z; acc[11] += p * v2.w;
            acc[12] += p * v3.x; acc[13] += p * v3.y; acc[14] += p * v3.z; acc[15] += p * v3.w;
        }
        // reduce across the 16-lane ch group (xor stays inside the group)
#pragma unroll
        for (int off = 1; off < 16; off <<= 1) {
            ps += __shfl_xor(ps, off, 64);
#pragma unroll
            for (int m = 0; m < 16; ++m) acc[m] += __shfl_xor(acc[m], off, 64);
        }
        if (ch == 0) {
            float inv = 1.0f / ps;
#pragma unroll
            for (int m = 0; m < 16; ++m) ovs[h][g][m] = acc[m] * inv;
        }
    }
    __syncthreads();                                 // all ovs ready

    // ---- output projection: thread = (o = t>>2, g = t&3); out (B,64,G,28,28) ----
    {
        int o = t >> 2, g = t & 3;
        float acc = b_out[o];
        const float4* wr = (const float4*)(w_out + o * 128);
#pragma unroll
        for (int c4 = 0; c4 < 32; ++c4) {
            float4 w4 = wr[c4];
            int c = c4 * 4;                          // mh = m*8 + h
            acc += w4.x * ovs[(c    ) & 7][g][(c    ) >> 3];
            acc += w4.y * ovs[(c + 1) & 7][g][(c + 1) >> 3];
            acc += w4.z * ovs[(c + 2) & 7][g][(c + 2) >> 3];
            acc += w4.w * ovs[(c + 3) & 7][g][(c + 3) >> 3];
        }
        out[((b * 64 + o) * 4 + g) * NPOS + ij] = acc;
    }
}

extern "C" void kernel_launch(void* const* d_in, const int* in_sizes, int n_in,
                              void* d_out, int out_size, void* d_ws, size_t ws_size,
                              hipStream_t stream)
{
    const float* x     = (const float*)d_in[0];
    const float* wq    = (const float*)d_in[1];
    const float* bq    = (const float*)d_in[2];
    const float* wk    = (const float*)d_in[3];
    const float* bk    = (const float*)d_in[4];
    const float* wv    = (const float*)d_in[5];
    const float* bv    = (const float*)d_in[6];
    const float* w_out = (const float*)d_in[7];
    const float* b_out = (const float*)d_in[8];
    const float* rw1 = (const float*)d_in[9];
    const float* rb1 = (const float*)d_in[10];
    const float* rga = (const float*)d_in[11];
    const float* rbe = (const float*)d_in[12];
    const float* rw2 = (const float*)d_in[13];
    const float* rb2 = (const float*)d_in[14];
    const float* cw1 = (const float*)d_in[15];
    const float* cb1 = (const float*)d_in[16];
    const float* cga = (const float*)d_in[17];
    const float* cbe = (const float*)d_in[18];
    const float* cw2 = (const float*)d_in[19];
    const float* cb2 = (const float*)d_in[20];
    // d_in[21]/d_in[22] (ridx/cidx) unused: closed-form rotation indices.

    float* Q = (float*)d_ws;                 // 3 x 401408 floats = 4.8 MB
    float* K = Q + 401408;
    float* V = K + 401408;

    qkv_kernel<<<1568, 256, 0, stream>>>(x, wq, bq, wk, bk, wv, bv, Q, K, V);
    attn_kernel<<<4 * NPOS, 256, 0, stream>>>(
        Q, K, V, w_out, b_out,
        rw1, rb1, rga, rbe, rw2, rb2,
        cw1, cb1, cga, cbe, cw2, cb2,
        (float*)d_out);
}